// Round 3
// baseline (1378.738 us; speedup 1.0000x reference)
//
#include <hip/hip_runtime.h>
#include <hip/hip_bf16.h>

#define NHEADS 16
#define HDIM   64
#define MDIM   1024
#define NTOK   121
#define NBATCH 1024

typedef __attribute__((ext_vector_type(4))) float f32x4;
typedef __attribute__((ext_vector_type(4))) short s16x4;
typedef __attribute__((ext_vector_type(8))) short s16x8;

// f32 -> bf16 RNE. Plain cast form so the compiler can fuse pairs into
// v_cvt_pk_bf16_f32 (m240: hand-written cvt_pk is slower than letting codegen do it).
__device__ __forceinline__ short f2bf(float f) {
  __hip_bfloat16 h = __float2bfloat16(f);
  return __builtin_bit_cast(short, h);
}

// ---------------------------------------------------------------------------
// Kernel 0: transpose+convert Wq/Wk/Wv (f32 [k][n]) -> bf16 Wt [n][k] in ws.
// ---------------------------------------------------------------------------
__global__ __launch_bounds__(256) void kTransW(const float* __restrict__ Wq,
                                               const float* __restrict__ Wk,
                                               const float* __restrict__ Wv,
                                               short* __restrict__ Wt) {
  int bid = blockIdx.x;
  int m = bid >> 8, tile = bid & 255;
  int tr = tile >> 4, tc = tile & 15;        // tr: k-tile, tc: n-tile (64x64)
  const float* W = (m == 0) ? Wq : (m == 1) ? Wk : Wv;
  short* T = Wt + (size_t)m * (MDIM * MDIM);
  __shared__ float tl[64][68];
  int t = threadIdx.x;
  int c4 = t & 15, r0 = t >> 4;
#pragma unroll
  for (int i = 0; i < 4; ++i) {
    int kr = r0 + i * 16;
    f32x4 v = *(const f32x4*)(W + (size_t)(tr * 64 + kr) * MDIM + tc * 64 + c4 * 4);
    *(f32x4*)&tl[kr][c4 * 4] = v;
  }
  __syncthreads();
#pragma unroll
  for (int i = 0; i < 4; ++i) {
    int n = r0 + i * 16;
    s16x4 o;
    o.x = f2bf(tl[c4 * 4 + 0][n]);
    o.y = f2bf(tl[c4 * 4 + 1][n]);
    o.z = f2bf(tl[c4 * 4 + 2][n]);
    o.w = f2bf(tl[c4 * 4 + 3][n]);
    *(s16x4*)(T + (size_t)(tc * 64 + n) * MDIM + tr * 64 + c4 * 4) = o;
  }
}

// ---------------------------------------------------------------------------
// GEMM core: C[128x128] = A[<=128 x 1024] * Wt-tile^T, fused f32->bf16 A.
// A: f32 global. Pipelined reg-stage: f32 loads for K-tile t+1 issue AFTER
//    barrier-2 (hide under MFMA phase, drained by next iteration's barrier-1,
//    which __syncthreads emits anyway); cvt+swizzled ds_write between barriers.
// B: bf16 Wt [n][k], global_load_lds (16B) with pre-swizzled source chunks.
// 256 threads = 4 waves (2x2), wave tile 64x64, mfma 16x16x32 bf16.
// LDS: [row][64] bf16, byte ^= (row&7)<<4 swizzle -> conflict-free ds_read_b128.
// ---------------------------------------------------------------------------
__device__ __forceinline__ void gemm_core(const float* __restrict__ A, int mrows,
                                          const short* __restrict__ Wt, int c0,
                                          short* Alds, short* Blds,
                                          f32x4 acc[4][4], int t) {
  int wid = t >> 6, lane = t & 63;
  int wr = wid >> 1, wc = wid & 1;
  int li = lane & 15, lg = lane >> 4;
  int kq = t & 15, r0s = t >> 4;     // A staging: rows r0s+16i, k-slice kq*4..kq*4+4
#pragma unroll
  for (int fm = 0; fm < 4; ++fm)
#pragma unroll
    for (int fn = 0; fn < 4; ++fn) acc[fm][fn] = (f32x4)0.0f;

  f32x4 rA[8];
  // prologue: issue A(0) f32 loads
#pragma unroll
  for (int i = 0; i < 8; ++i) {
    int row = r0s + (i << 4);
    rA[i] = (row < mrows) ? *(const f32x4*)(A + (size_t)row * MDIM + kq * 4)
                          : (f32x4)0.0f;
  }

#pragma unroll
  for (int kt = 0; kt < 16; ++kt) {
    int k0 = kt * 64;
    __syncthreads();                 // (1) prev readers done; rA(kt) drained (vmcnt 0)
    // ---- issue B gload_lds for this K-tile (flies across the cvt phase)
#pragma unroll
    for (int i = 0; i < 4; ++i) {
      int cl = wid * 32 + i * 8 + (lane >> 3);
      int jg = (lane & 7) ^ (cl & 7);
      const short* g = Wt + (size_t)(c0 + cl) * MDIM + k0 + jg * 8;
      short* lb = Blds + (wid * 32 + i * 8) * 64;   // wave-uniform base
      __builtin_amdgcn_global_load_lds((const __attribute__((address_space(1))) void*)g,
                                       (__attribute__((address_space(3))) void*)lb,
                                       16, 0, 0);
    }
    // ---- cvt rA(kt) -> bf16, swizzled ds_write
#pragma unroll
    for (int i = 0; i < 8; ++i) {
      int row = r0s + (i << 4);
      s16x4 b4;
      b4.x = f2bf(rA[i].x); b4.y = f2bf(rA[i].y);
      b4.z = f2bf(rA[i].z); b4.w = f2bf(rA[i].w);
      int byte = (row * 128 + kq * 8) ^ ((row & 7) << 4);
      *(s16x4*)((char*)Alds + byte) = b4;
    }
    __syncthreads();                 // (2) drains B glds; A ds_writes visible
    // ---- prefetch A(kt+1) f32 -> regs; latency hides under MFMA phase
    if (kt < 15) {
#pragma unroll
      for (int i = 0; i < 8; ++i) {
        int row = r0s + (i << 4);
        rA[i] = (row < mrows)
                    ? *(const f32x4*)(A + (size_t)row * MDIM + k0 + 64 + kq * 4)
                    : (f32x4)0.0f;
      }
    }
    // ---- MFMA over the 64-k tile (2 x k=32 steps)
#pragma unroll
    for (int ks = 0; ks < 2; ++ks) {
      s16x8 af[4], bf[4];
      int kb = ks * 64 + lg * 16;
#pragma unroll
      for (int fm = 0; fm < 4; ++fm) {
        int row = wr * 64 + fm * 16 + li;
        int byte = (row * 128 + kb) ^ ((row & 7) << 4);
        af[fm] = *(s16x8*)((char*)Alds + byte);
      }
#pragma unroll
      for (int fn = 0; fn < 4; ++fn) {
        int col = wc * 64 + fn * 16 + li;
        int byte = (col * 128 + kb) ^ ((col & 7) << 4);
        bf[fn] = *(s16x8*)((char*)Blds + byte);
      }
#pragma unroll
      for (int fm = 0; fm < 4; ++fm)
#pragma unroll
        for (int fn = 0; fn < 4; ++fn)
          acc[fm][fn] = __builtin_amdgcn_mfma_f32_16x16x32_bf16(af[fm], bf[fn],
                                                                acc[fm][fn], 0, 0, 0);
    }
  }
}

// ---------------------------------------------------------------------------
// q_proj = query @ Wq + bq  -> f32 into d_out's output region (scratch)
// ---------------------------------------------------------------------------
__global__ __launch_bounds__(256, 3) void kQProj(const float* __restrict__ query,
                                                 const short* __restrict__ WtQ,
                                                 const float* __restrict__ bq,
                                                 float* __restrict__ qproj) {
  __shared__ alignas(16) short Alds[128 * 64];
  __shared__ alignas(16) short Blds[128 * 64];
  int bid = blockIdx.x;
  int rt = bid >> 3, ct = bid & 7;
  f32x4 acc[4][4];
  int t = threadIdx.x;
  gemm_core(query + (size_t)rt * 128 * MDIM, 128, WtQ, ct * 128, Alds, Blds, acc, t);
  int wid = t >> 6, lane = t & 63;
  int wr = wid >> 1, wc = wid & 1, li = lane & 15, lg = lane >> 4;
#pragma unroll
  for (int fn = 0; fn < 4; ++fn) {
    int col = ct * 128 + wc * 64 + fn * 16 + li;
    float bqv = bq[col];
#pragma unroll
    for (int fm = 0; fm < 4; ++fm)
#pragma unroll
      for (int rr = 0; rr < 4; ++rr) {
        int row = rt * 128 + wr * 64 + fm * 16 + lg * 4 + rr;
        qproj[(size_t)row * MDIM + col] = acc[fm][fn][rr] + bqv;
      }
  }
}

// ---------------------------------------------------------------------------
// k-GEMM fused with scores + softmax -> writes weights [B,H,121] (f32, d_out)
// ---------------------------------------------------------------------------
__global__ __launch_bounds__(256, 3) void kScores(const float* __restrict__ key,
                                                  const short* __restrict__ WtK,
                                                  const float* __restrict__ bk,
                                                  const float* __restrict__ qproj,
                                                  float* __restrict__ weights) {
  __shared__ alignas(16) short Alds[128 * 64];
  __shared__ alignas(16) short Blds[128 * 64];
  __shared__ float s_lds[2][128];
  int bid = blockIdx.x;
  int lbid = (bid & 7) * 1024 + (bid >> 3);   // XCD-chunked: one batch's 8 ct on one XCD
  int b = lbid >> 3, ct = lbid & 7;
  f32x4 acc[4][4];
  int t = threadIdx.x;
  gemm_core(key + (size_t)b * NTOK * MDIM, NTOK, WtK, ct * 128, Alds, Blds, acc, t);
  int wid = t >> 6, lane = t & 63;
  int wr = wid >> 1, wc = wid & 1, li = lane & 15, lg = lane >> 4;
  float qv[4], bkv[4];
#pragma unroll
  for (int fn = 0; fn < 4; ++fn) {
    int col = ct * 128 + wc * 64 + fn * 16 + li;
    qv[fn]  = qproj[(size_t)b * MDIM + col];
    bkv[fn] = bk[col];
  }
#pragma unroll
  for (int fm = 0; fm < 4; ++fm)
#pragma unroll
    for (int rr = 0; rr < 4; ++rr) {
      float p = 0.f;
#pragma unroll
      for (int fn = 0; fn < 4; ++fn) p += (acc[fm][fn][rr] + bkv[fn]) * qv[fn];
      p += __shfl_xor(p, 1); p += __shfl_xor(p, 2);
      p += __shfl_xor(p, 4); p += __shfl_xor(p, 8);
      if (li == 0) {
        int n = wr * 64 + fm * 16 + lg * 4 + rr;
        s_lds[wc][n] = p;
      }
    }
  __syncthreads();
  if (wid < 2) {
    int hg = ct * 2 + wid;
    int n0 = lane, n1 = lane + 64;
    bool v0 = (n0 < NTOK), v1 = (n1 < NTOK);
    float w0, w1;
    if (hg == 0 || hg == 3) {                 // disturb heads: uniform weights
      w0 = 1.f / NTOK; w1 = 1.f / NTOK;
    } else {
      const float kinv = 1.f / 32.f;          // 1/sqrt(d*H)
      float s0 = v0 ? s_lds[wid][n0] * kinv : -1e30f;
      float s1 = v1 ? s_lds[wid][n1] * kinv : -1e30f;
      float m = fmaxf(s0, s1);
#pragma unroll
      for (int msk = 1; msk < 64; msk <<= 1) m = fmaxf(m, __shfl_xor(m, msk));
      float e0 = v0 ? __expf(s0 - m) : 0.f;
      float e1 = v1 ? __expf(s1 - m) : 0.f;
      float s = e0 + e1;
#pragma unroll
      for (int msk = 1; msk < 64; msk <<= 1) s += __shfl_xor(s, msk);
      float inv = 1.f / s;
      w0 = e0 * inv; w1 = e1 * inv;
    }
    float* wp = weights + ((size_t)b * NHEADS + hg) * NTOK;
    if (v0) wp[n0] = w0;
    if (v1) wp[n1] = w1;
  }
}

// ---------------------------------------------------------------------------
// v-GEMM fused with weighted reduction -> output [B, 1024] (f32, d_out)
// ---------------------------------------------------------------------------
__global__ __launch_bounds__(256, 3) void kOut(const float* __restrict__ value,
                                               const short* __restrict__ WtV,
                                               const float* __restrict__ bv,
                                               const float* __restrict__ weights,
                                               float* __restrict__ outp) {
  __shared__ alignas(16) short Alds[128 * 64];
  __shared__ alignas(16) short Blds[128 * 64];
  __shared__ float w_lds[2][128];
  __shared__ float outacc[128];
  int bid = blockIdx.x;
  int lbid = (bid & 7) * 1024 + (bid >> 3);
  int b = lbid >> 3, ct = lbid & 7;
  int t = threadIdx.x;
  {
    int hl = t >> 7, n = t & 127;
    w_lds[hl][n] = (n < NTOK)
        ? weights[((size_t)b * NHEADS + ct * 2 + hl) * NTOK + n] : 0.f;
  }
  f32x4 acc[4][4];
  gemm_core(value + (size_t)b * NTOK * MDIM, NTOK, WtV, ct * 128, Alds, Blds, acc, t);
  int wid = t >> 6, lane = t & 63;
  int wr = wid >> 1, wc = wid & 1, li = lane & 15, lg = lane >> 4;
  float sum4[4] = {0.f, 0.f, 0.f, 0.f};
#pragma unroll
  for (int fm = 0; fm < 4; ++fm)
#pragma unroll
    for (int rr = 0; rr < 4; ++rr) {
      int n = wr * 64 + fm * 16 + lg * 4 + rr;
      float wv = w_lds[wc][n];                  // 0 for n>=121 (pad rows are zeroed anyway)
#pragma unroll
      for (int fn = 0; fn < 4; ++fn) sum4[fn] += acc[fm][fn][rr] * wv;
    }
#pragma unroll
  for (int fn = 0; fn < 4; ++fn) {
    sum4[fn] += __shfl_xor(sum4[fn], 16);
    sum4[fn] += __shfl_xor(sum4[fn], 32);
  }
  if (wr == 0 && lane < 16) {
#pragma unroll
    for (int fn = 0; fn < 4; ++fn) outacc[wc * 64 + fn * 16 + lane] = sum4[fn];
  }
  __syncthreads();
  if (wr == 1 && lane < 16) {
#pragma unroll
    for (int fn = 0; fn < 4; ++fn) outacc[wc * 64 + fn * 16 + lane] += sum4[fn];
  }
  __syncthreads();
  if (t < 128) {
    int col = ct * 128 + t;
    outp[(size_t)b * MDIM + col] = outacc[t] + bv[col];
  }
}

// ---------------------------------------------------------------------------
extern "C" void kernel_launch(void* const* d_in, const int* in_sizes, int n_in,
                              void* d_out, int out_size, void* d_ws, size_t ws_size,
                              hipStream_t stream) {
  const float* query = (const float*)d_in[0];
  const float* key   = (const float*)d_in[1];
  const float* value = (const float*)d_in[2];
  const float* Wq    = (const float*)d_in[3];
  const float* bq    = (const float*)d_in[4];
  const float* Wk    = (const float*)d_in[5];
  const float* bk    = (const float*)d_in[6];
  const float* Wv    = (const float*)d_in[7];
  const float* bv    = (const float*)d_in[8];

  float* out     = (float*)d_out;
  float* weights = out + (size_t)NBATCH * MDIM;
  float* qproj   = out;                          // output region reused as scratch

  short* Wt = (short*)d_ws;                      // 3 x 1M bf16 = 6 MB

  kTransW<<<dim3(768),  dim3(256), 0, stream>>>(Wq, Wk, Wv, Wt);
  kQProj <<<dim3(64),   dim3(256), 0, stream>>>(query, Wt, bq, qproj);
  kScores<<<dim3(8192), dim3(256), 0, stream>>>(
      key, Wt + (size_t)MDIM * MDIM, bk, qproj, weights);
  kOut   <<<dim3(8192), dim3(256), 0, stream>>>(
      value, Wt + 2 * (size_t)MDIM * MDIM, bv, weights, out);
}

// Round 4
// 730.663 us; speedup vs baseline: 1.8870x; 1.8870x over previous
//
#include <hip/hip_runtime.h>
#include <hip/hip_bf16.h>

#define NHEADS 16
#define HDIM   64
#define MDIM   1024
#define NTOK   121
#define NBATCH 1024

typedef __attribute__((ext_vector_type(4))) float f32x4;
typedef __attribute__((ext_vector_type(4))) short s16x4;
typedef __attribute__((ext_vector_type(8))) short s16x8;

// f32 -> bf16 RNE (compiler fuses pairs into v_cvt_pk_bf16_f32; m240)
__device__ __forceinline__ short f2bf(float f) {
  __hip_bfloat16 h = __float2bfloat16(f);
  return __builtin_bit_cast(short, h);
}

// ---------------------------------------------------------------------------
// Kernel 0: transpose+convert Wq/Wk/Wv (f32 [k][n]) -> bf16 Wt [n][k] in ws.
// ---------------------------------------------------------------------------
__global__ __launch_bounds__(256) void kTransW(const float* __restrict__ Wq,
                                               const float* __restrict__ Wk,
                                               const float* __restrict__ Wv,
                                               short* __restrict__ Wt) {
  int bid = blockIdx.x;
  int m = bid >> 8, tile = bid & 255;
  int tr = tile >> 4, tc = tile & 15;        // tr: k-tile, tc: n-tile (64x64)
  const float* W = (m == 0) ? Wq : (m == 1) ? Wk : Wv;
  short* T = Wt + (size_t)m * (MDIM * MDIM);
  __shared__ float tl[64][68];
  int t = threadIdx.x;
  int c4 = t & 15, r0 = t >> 4;
#pragma unroll
  for (int i = 0; i < 4; ++i) {
    int kr = r0 + i * 16;
    f32x4 v = *(const f32x4*)(W + (size_t)(tr * 64 + kr) * MDIM + tc * 64 + c4 * 4);
    *(f32x4*)&tl[kr][c4 * 4] = v;
  }
  __syncthreads();
#pragma unroll
  for (int i = 0; i < 4; ++i) {
    int n = r0 + i * 16;
    s16x4 o;
    o.x = f2bf(tl[c4 * 4 + 0][n]);
    o.y = f2bf(tl[c4 * 4 + 1][n]);
    o.z = f2bf(tl[c4 * 4 + 2][n]);
    o.w = f2bf(tl[c4 * 4 + 3][n]);
    *(s16x4*)(T + (size_t)(tc * 64 + n) * MDIM + tr * 64 + c4 * 4) = o;
  }
}

// ---------------------------------------------------------------------------
// GEMM core: C[128x128] = A[<=128 x 1024] * Wt-tile^T, fused f32->bf16 A.
//
// Register-budget design (round-3 spill post-mortem): with launch_bounds
// (256,3) the unified VGPR/AGPR cap is ~168/wave. acc(64 AGPR) + af/bf(32)
// means only ~16 regs may live across the MFMA phase. So:
//   - rLo (rows 0..63, 4x f32x4 = 16 regs) prefetched after barrier-2,
//     latency hidden under the MFMA phase, drained by next barrier-1.
//   - rHi (rows 64..127) loaded at stage time, issued BEFORE the B
//     global_load_lds so cvt-hi waits at vmcnt(4); latency hidden under
//     cvt-lo + other resident blocks' MFMA.
// Rows are clamped (min(row, mrows-1)) instead of predicated: duplicate
// row-120 results are ignored downstream (softmax reads n<121; kOut
// multiplies n>=121 by weight 0).
// B: bf16 Wt [n][k], global_load_lds (16B) with pre-swizzled source chunks.
// 256 threads = 4 waves (2x2), wave tile 64x64, mfma 16x16x32 bf16.
// LDS: [row][64] bf16, byte ^= (row&7)<<4 swizzle -> conflict-free ds_read_b128.
// ---------------------------------------------------------------------------
__device__ __forceinline__ void gemm_core(const float* __restrict__ A, int mrows,
                                          const short* __restrict__ Wt, int c0,
                                          short* Alds, short* Blds,
                                          f32x4 acc[4][4], int t) {
  int wid = t >> 6, lane = t & 63;
  int wr = wid >> 1, wc = wid & 1;
  int li = lane & 15, lg = lane >> 4;
  int kq = t & 15, r0s = t >> 4;     // A staging: rows r0s+16i, bytes kq*16..
#pragma unroll
  for (int fm = 0; fm < 4; ++fm)
#pragma unroll
    for (int fn = 0; fn < 4; ++fn) acc[fm][fn] = (f32x4)0.0f;

  // clamped hi-row indices (rows 64..127; clamp matters only when mrows=121)
  int rhi[4];
#pragma unroll
  for (int i = 0; i < 4; ++i) {
    int row = r0s + 64 + (i << 4);
    rhi[i] = row < mrows ? row : mrows - 1;
  }

  f32x4 rLo[4];                      // rows 0..63 are always valid
#pragma unroll
  for (int i = 0; i < 4; ++i)
    rLo[i] = *(const f32x4*)(A + (size_t)(r0s + (i << 4)) * MDIM + kq * 4);

  for (int kt = 0; kt < 16; ++kt) {
    int k0 = kt * 64;
    __syncthreads();                 // (1) prev readers done; rLo drained (vmcnt 0)
    // ---- issue A-hi loads first (oldest in queue -> cvt-hi waits vmcnt(4))
    f32x4 rHi[4];
#pragma unroll
    for (int i = 0; i < 4; ++i)
      rHi[i] = *(const f32x4*)(A + (size_t)rhi[i] * MDIM + k0 + kq * 4);
    // ---- issue B gload_lds for this K-tile (drained by barrier-2)
#pragma unroll
    for (int i = 0; i < 4; ++i) {
      int cl = wid * 32 + i * 8 + (lane >> 3);
      int jg = (lane & 7) ^ (cl & 7);
      const short* g = Wt + (size_t)(c0 + cl) * MDIM + k0 + jg * 8;
      short* lb = Blds + (wid * 32 + i * 8) * 64;   // wave-uniform base
      __builtin_amdgcn_global_load_lds((const __attribute__((address_space(1))) void*)g,
                                       (__attribute__((address_space(3))) void*)lb,
                                       16, 0, 0);
    }
    // ---- cvt + swizzled ds_write: lo rows (data already resident)
#pragma unroll
    for (int i = 0; i < 4; ++i) {
      int row = r0s + (i << 4);
      s16x4 b4;
      b4.x = f2bf(rLo[i].x); b4.y = f2bf(rLo[i].y);
      b4.z = f2bf(rLo[i].z); b4.w = f2bf(rLo[i].w);
      int byte = (row * 128 + kq * 8) ^ ((row & 7) << 4);
      *(s16x4*)((char*)Alds + byte) = b4;
    }
    // ---- cvt + ds_write: hi rows (waits rHi at vmcnt(4))
#pragma unroll
    for (int i = 0; i < 4; ++i) {
      int row = r0s + 64 + (i << 4);
      s16x4 b4;
      b4.x = f2bf(rHi[i].x); b4.y = f2bf(rHi[i].y);
      b4.z = f2bf(rHi[i].z); b4.w = f2bf(rHi[i].w);
      int byte = (row * 128 + kq * 8) ^ ((row & 7) << 4);
      *(s16x4*)((char*)Alds + byte) = b4;
    }
    __syncthreads();                 // (2) drains B glds; A ds_writes visible
    // ---- prefetch A-lo(kt+1); latency hides under MFMA, drains at barrier-1
    {
      int k1 = (kt < 15) ? k0 + 64 : 0;   // kt=15: dummy re-read of k=0 (in-bounds)
#pragma unroll
      for (int i = 0; i < 4; ++i)
        rLo[i] = *(const f32x4*)(A + (size_t)(r0s + (i << 4)) * MDIM + k1 + kq * 4);
    }
    // ---- MFMA over the 64-k tile (2 x k=32 steps)
#pragma unroll
    for (int ks = 0; ks < 2; ++ks) {
      s16x8 af[4], bf[4];
      int kb = ks * 64 + lg * 16;
#pragma unroll
      for (int fm = 0; fm < 4; ++fm) {
        int row = wr * 64 + fm * 16 + li;
        int byte = (row * 128 + kb) ^ ((row & 7) << 4);
        af[fm] = *(s16x8*)((char*)Alds + byte);
      }
#pragma unroll
      for (int fn = 0; fn < 4; ++fn) {
        int col = wc * 64 + fn * 16 + li;
        int byte = (col * 128 + kb) ^ ((col & 7) << 4);
        bf[fn] = *(s16x8*)((char*)Blds + byte);
      }
#pragma unroll
      for (int fm = 0; fm < 4; ++fm)
#pragma unroll
        for (int fn = 0; fn < 4; ++fn)
          acc[fm][fn] = __builtin_amdgcn_mfma_f32_16x16x32_bf16(af[fm], bf[fn],
                                                                acc[fm][fn], 0, 0, 0);
    }
  }
}

// ---------------------------------------------------------------------------
// q_proj = query @ Wq + bq  -> f32 into d_out's output region (scratch)
// ---------------------------------------------------------------------------
__global__ __launch_bounds__(256, 3) void kQProj(const float* __restrict__ query,
                                                 const short* __restrict__ WtQ,
                                                 const float* __restrict__ bq,
                                                 float* __restrict__ qproj) {
  __shared__ alignas(16) short Alds[128 * 64];
  __shared__ alignas(16) short Blds[128 * 64];
  int bid = blockIdx.x;
  int rt = bid >> 3, ct = bid & 7;
  f32x4 acc[4][4];
  int t = threadIdx.x;
  gemm_core(query + (size_t)rt * 128 * MDIM, 128, WtQ, ct * 128, Alds, Blds, acc, t);
  int wid = t >> 6, lane = t & 63;
  int wr = wid >> 1, wc = wid & 1, li = lane & 15, lg = lane >> 4;
#pragma unroll
  for (int fn = 0; fn < 4; ++fn) {
    int col = ct * 128 + wc * 64 + fn * 16 + li;
    float bqv = bq[col];
#pragma unroll
    for (int fm = 0; fm < 4; ++fm)
#pragma unroll
      for (int rr = 0; rr < 4; ++rr) {
        int row = rt * 128 + wr * 64 + fm * 16 + lg * 4 + rr;
        qproj[(size_t)row * MDIM + col] = acc[fm][fn][rr] + bqv;
      }
  }
}

// ---------------------------------------------------------------------------
// k-GEMM fused with scores + softmax -> writes weights [B,H,121] (f32, d_out)
// ---------------------------------------------------------------------------
__global__ __launch_bounds__(256, 3) void kScores(const float* __restrict__ key,
                                                  const short* __restrict__ WtK,
                                                  const float* __restrict__ bk,
                                                  const float* __restrict__ qproj,
                                                  float* __restrict__ weights) {
  __shared__ alignas(16) short Alds[128 * 64];
  __shared__ alignas(16) short Blds[128 * 64];
  __shared__ float s_lds[2][128];
  int bid = blockIdx.x;
  int lbid = (bid & 7) * 1024 + (bid >> 3);   // XCD-chunked: one batch's 8 ct on one XCD
  int b = lbid >> 3, ct = lbid & 7;
  f32x4 acc[4][4];
  int t = threadIdx.x;
  gemm_core(key + (size_t)b * NTOK * MDIM, NTOK, WtK, ct * 128, Alds, Blds, acc, t);
  int wid = t >> 6, lane = t & 63;
  int wr = wid >> 1, wc = wid & 1, li = lane & 15, lg = lane >> 4;
  float qv[4], bkv[4];
#pragma unroll
  for (int fn = 0; fn < 4; ++fn) {
    int col = ct * 128 + wc * 64 + fn * 16 + li;
    qv[fn]  = qproj[(size_t)b * MDIM + col];
    bkv[fn] = bk[col];
  }
#pragma unroll
  for (int fm = 0; fm < 4; ++fm)
#pragma unroll
    for (int rr = 0; rr < 4; ++rr) {
      float p = 0.f;
#pragma unroll
      for (int fn = 0; fn < 4; ++fn) p += (acc[fm][fn][rr] + bkv[fn]) * qv[fn];
      p += __shfl_xor(p, 1); p += __shfl_xor(p, 2);
      p += __shfl_xor(p, 4); p += __shfl_xor(p, 8);
      if (li == 0) {
        int n = wr * 64 + fm * 16 + lg * 4 + rr;
        s_lds[wc][n] = p;
      }
    }
  __syncthreads();
  if (wid < 2) {
    int hg = ct * 2 + wid;
    int n0 = lane, n1 = lane + 64;
    bool v0 = (n0 < NTOK), v1 = (n1 < NTOK);
    float w0, w1;
    if (hg == 0 || hg == 3) {                 // disturb heads: uniform weights
      w0 = 1.f / NTOK; w1 = 1.f / NTOK;
    } else {
      const float kinv = 1.f / 32.f;          // 1/sqrt(d*H)
      float s0 = v0 ? s_lds[wid][n0] * kinv : -1e30f;
      float s1 = v1 ? s_lds[wid][n1] * kinv : -1e30f;
      float m = fmaxf(s0, s1);
#pragma unroll
      for (int msk = 1; msk < 64; msk <<= 1) m = fmaxf(m, __shfl_xor(m, msk));
      float e0 = v0 ? __expf(s0 - m) : 0.f;
      float e1 = v1 ? __expf(s1 - m) : 0.f;
      float s = e0 + e1;
#pragma unroll
      for (int msk = 1; msk < 64; msk <<= 1) s += __shfl_xor(s, msk);
      float inv = 1.f / s;
      w0 = e0 * inv; w1 = e1 * inv;
    }
    float* wp = weights + ((size_t)b * NHEADS + hg) * NTOK;
    if (v0) wp[n0] = w0;
    if (v1) wp[n1] = w1;
  }
}

// ---------------------------------------------------------------------------
// v-GEMM fused with weighted reduction -> output [B, 1024] (f32, d_out)
// ---------------------------------------------------------------------------
__global__ __launch_bounds__(256, 3) void kOut(const float* __restrict__ value,
                                               const short* __restrict__ WtV,
                                               const float* __restrict__ bv,
                                               const float* __restrict__ weights,
                                               float* __restrict__ outp) {
  __shared__ alignas(16) short Alds[128 * 64];
  __shared__ alignas(16) short Blds[128 * 64];
  __shared__ float w_lds[2][128];
  __shared__ float outacc[128];
  int bid = blockIdx.x;
  int lbid = (bid & 7) * 1024 + (bid >> 3);
  int b = lbid >> 3, ct = lbid & 7;
  int t = threadIdx.x;
  {
    int hl = t >> 7, n = t & 127;
    w_lds[hl][n] = (n < NTOK)
        ? weights[((size_t)b * NHEADS + ct * 2 + hl) * NTOK + n] : 0.f;
  }
  f32x4 acc[4][4];
  gemm_core(value + (size_t)b * NTOK * MDIM, NTOK, WtV, ct * 128, Alds, Blds, acc, t);
  int wid = t >> 6, lane = t & 63;
  int wr = wid >> 1, wc = wid & 1, li = lane & 15, lg = lane >> 4;
  float sum4[4] = {0.f, 0.f, 0.f, 0.f};
#pragma unroll
  for (int fm = 0; fm < 4; ++fm)
#pragma unroll
    for (int rr = 0; rr < 4; ++rr) {
      int n = wr * 64 + fm * 16 + lg * 4 + rr;
      float wv = w_lds[wc][n];                  // 0 for n>=121 (dup rows ignored)
#pragma unroll
      for (int fn = 0; fn < 4; ++fn) sum4[fn] += acc[fm][fn][rr] * wv;
    }
#pragma unroll
  for (int fn = 0; fn < 4; ++fn) {
    sum4[fn] += __shfl_xor(sum4[fn], 16);
    sum4[fn] += __shfl_xor(sum4[fn], 32);
  }
  if (wr == 0 && lane < 16) {
#pragma unroll
    for (int fn = 0; fn < 4; ++fn) outacc[wc * 64 + fn * 16 + lane] = sum4[fn];
  }
  __syncthreads();
  if (wr == 1 && lane < 16) {
#pragma unroll
    for (int fn = 0; fn < 4; ++fn) outacc[wc * 64 + fn * 16 + lane] += sum4[fn];
  }
  __syncthreads();
  if (t < 128) {
    int col = ct * 128 + t;
    outp[(size_t)b * MDIM + col] = outacc[t] + bv[col];
  }
}

// ---------------------------------------------------------------------------
extern "C" void kernel_launch(void* const* d_in, const int* in_sizes, int n_in,
                              void* d_out, int out_size, void* d_ws, size_t ws_size,
                              hipStream_t stream) {
  const float* query = (const float*)d_in[0];
  const float* key   = (const float*)d_in[1];
  const float* value = (const float*)d_in[2];
  const float* Wq    = (const float*)d_in[3];
  const float* bq    = (const float*)d_in[4];
  const float* Wk    = (const float*)d_in[5];
  const float* bk    = (const float*)d_in[6];
  const float* Wv    = (const float*)d_in[7];
  const float* bv    = (const float*)d_in[8];

  float* out     = (float*)d_out;
  float* weights = out + (size_t)NBATCH * MDIM;
  float* qproj   = out;                          // output region reused as scratch

  short* Wt = (short*)d_ws;                      // 3 x 1M bf16 = 6 MB

  kTransW<<<dim3(768),  dim3(256), 0, stream>>>(Wq, Wk, Wv, Wt);
  kQProj <<<dim3(64),   dim3(256), 0, stream>>>(query, Wt, bq, qproj);
  kScores<<<dim3(8192), dim3(256), 0, stream>>>(
      key, Wt + (size_t)MDIM * MDIM, bk, qproj, weights);
  kOut   <<<dim3(8192), dim3(256), 0, stream>>>(
      value, Wt + 2 * (size_t)MDIM * MDIM, bv, weights, out);
}